// Round 4
// baseline (228.869 us; speedup 1.0000x reference)
//
#include <hip/hip_runtime.h>

typedef short bf16x8 __attribute__((ext_vector_type(8)));
typedef float f32x4 __attribute__((ext_vector_type(4)));
typedef unsigned short u16;
typedef unsigned int u32;

static __device__ __forceinline__ u16 f2bf(float f) {
  u32 u = __builtin_bit_cast(u32, f);
  u32 r = (u + 0x7FFFu + ((u >> 16) & 1u)) >> 16;  // RNE
  return (u16)r;
}

// ---- kernel 0: one-time f32 -> bf16 weight conversion + FRAGMENT SWIZZLE ----
// wqkv chunks (cid < 24576): tile = cid>>9 (tile = s*16+h*2+u), k = (cid>>6)&7,
//   lane = cid&63; 16B chunk = W[tile*16+(lane&15)][k*32+(lane>>4)*8 .. +8],
//   stored at wbf + cid*8 (linear).
// wproj (pid < 8192): mt = pid>>9, h = (pid>>6)&7, lane = pid&63 — stored
//   HEAD-MAJOR so each head's proj slice is contiguous (two 8 KB halves):
//   dst chunk = 24576 + h*1024 + mt*64 + lane.
__global__ __launch_bounds__(256) void k_conv(
    const float* __restrict__ wqkv, const float* __restrict__ wproj,
    u16* __restrict__ wbf) {
  const int cid = blockIdx.x * 256 + threadIdx.x;  // 128 blocks -> 32768 chunks
  const float* src;
  int dst;
  if (cid < 24576) {
    const int tile = cid >> 9, rem = cid & 511;
    const int k = rem >> 6, lane = rem & 63;
    src = wqkv + (size_t)(tile * 16 + (lane & 15)) * 256 + k * 32 + (lane >> 4) * 8;
    dst = cid;
  } else {
    const int pid = cid - 24576;
    const int mt = pid >> 9, rem = pid & 511;
    const int h = rem >> 6, lane = rem & 63;
    src = wproj + (size_t)(mt * 16 + (lane & 15)) * 256 + h * 32 + (lane >> 4) * 8;
    dst = 24576 + h * 1024 + mt * 64 + lane;
  }
  float4 f0 = *(const float4*)(src);
  float4 f1 = *(const float4*)(src + 4);
  ushort4 a, b;
  a.x = f2bf(f0.x); a.y = f2bf(f0.y); a.z = f2bf(f0.z); a.w = f2bf(f0.w);
  b.x = f2bf(f1.x); b.y = f2bf(f1.y); b.z = f2bf(f1.z); b.w = f2bf(f1.w);
  *(ushort4*)(wbf + (size_t)dst * 8) = a;
  *(ushort4*)(wbf + (size_t)dst * 8 + 4) = b;
}

// Two windows per block (512 thr, 8 waves): waves 0-3 = side 0, 4-7 = side 1.
// Each staged 8 KB weight unit feeds BOTH windows -> per-CU DMA demand halves
// (the measured pin was ~6 B/cy/CU of global_load_lds across R0-R3).
//
// LDS map (u16), time-disjoint overlays — total 64512 B -> 2 blocks/CU:
//   BUF0 [0,4096)  BUF1 [4096,8192)          weight stage buffers (8 KB each)
//   ATT(side) = 8192 + side*12032:
//     QH +0 (64x40) | KH +2560 (64x40) | VTH +5120 (32x72) | P +7424 (4x[16][72])
//   X overlay [0,16896)  — phase 1 only, one window staged at a time
#define BUF0 0
#define BUF1 4096
#define ATT_BASE 8192
#define ATT_STRIDE 12032
#define KH_OFF 2560
#define VTH_OFF 5120
#define P_OFF 7424
#define LDS_TOT 32256

#define MEMF() asm volatile("" ::: "memory")
// Single-barrier unit entry: drain own DMA (vmcnt) + own LDS ops (lgkm), then
// barrier. After this: (a) this unit's staged slice is visible to all waves,
// (b) every wave's reads of the buffer the upcoming stage overwrites are done.
// The waited stage was issued a full unit ago (flight ~= one period).
#define ENTRY()                                                      \
  do {                                                               \
    asm volatile("s_waitcnt vmcnt(0) lgkmcnt(0)" ::: "memory");      \
    __builtin_amdgcn_s_barrier();                                    \
    MEMF();                                                          \
  } while (0)

#define GL2LDS(gp, lp)                                   \
  __builtin_amdgcn_global_load_lds(                      \
      (__attribute__((address_space(1))) void*)(gp),     \
      (__attribute__((address_space(3))) void*)(lp), 16, 0, 0)

// stage one 4096-u16 (8 KB) unit: 1 x global_load_lds dwordx4 per thread (512
// threads x 16 B). LDS dest linear = pre-swizzled global order (verbatim copy).
static __device__ __forceinline__ void stage1(const u16* g, u16* l, int t) {
  GL2LDS(g + t * 8, l + t * 8);
}

// one 16-c_out QKV tile from staged buffer BUFB -> row store at col U*16
#define QKV_TILE(BUFB, DSTB, U)                                           \
  do {                                                                    \
    const u16* wb_ = LDS + (BUFB) + lane * 8;                             \
    f32x4 acc = {0.f, 0.f, 0.f, 0.f};                                     \
    _Pragma("unroll") for (int k = 0; k < 8; ++k) acc =                   \
        __builtin_amdgcn_mfma_f32_16x16x32_bf16(                          \
            af[k], *(const bf16x8*)(wb_ + k * 512), acc, 0, 0, 0);        \
    _Pragma("unroll") for (int r = 0; r < 4; ++r)                         \
        LDS[(DSTB) + (pos0 + r) * 40 + (U) * 16 + l15] = f2bf(acc[r]);    \
  } while (0)

// one 16-c_out V tile -> VTHs transposed [hd][pos]
#define V_TILE(BUFB, U)                                                   \
  do {                                                                    \
    const u16* wb_ = LDS + (BUFB) + lane * 8;                             \
    f32x4 acc = {0.f, 0.f, 0.f, 0.f};                                     \
    _Pragma("unroll") for (int k = 0; k < 8; ++k) acc =                   \
        __builtin_amdgcn_mfma_f32_16x16x32_bf16(                          \
            af[k], *(const bf16x8*)(wb_ + k * 512), acc, 0, 0, 0);        \
    ushort4 pk;                                                           \
    pk.x = f2bf(acc[0]); pk.y = f2bf(acc[1]);                             \
    pk.z = f2bf(acc[2]); pk.w = f2bf(acc[3]);                             \
    *(ushort4*)&LDS[VTHs + ((U) * 16 + l15) * 72 + pos0] = pk;            \
  } while (0)

__global__ __launch_bounds__(512, 4) void k_fused(
    const float* __restrict__ x, const u16* __restrict__ wbf,
    const int* __restrict__ shiftp, float* __restrict__ out) {
  __shared__ u16 LDS[LDS_TOT];
  // XCD-locality: the 4 window-pairs sharing (b,wh) x/out cache lines get
  // block IDs congruent mod 128 -> same XCD under round-robin dispatch.
  const int blk = blockIdx.x;                       // 0..511
  const int pair = ((blk & 127) << 2) | (blk >> 7); // b*32 + wh*4 + wwp
  const int b = pair >> 5, wh = (pair >> 2) & 7, wwp = pair & 3;
  const int off = (shiftp[0] != 0) ? 4 : 0;
  const int t = threadIdx.x;                        // 0..511
  const int side = t >> 8;                          // which window of the pair
  const int ww = wwp * 2 + side;

  // stagger the 2 co-resident blocks (blk, blk+256) by ~ half a unit period
  if ((blk >> 8) & 1) __builtin_amdgcn_s_sleep(24);

  const int lane = t & 63, wv = (t >> 6) & 3;  // wave (within side) owns 16 pos
  const int l15 = lane & 15, quad = lane >> 4;
  const int pos0 = wv * 16 + quad * 4;

  // ---- phase 1: stage rolled X for the two windows, one at a time, through
  // the shared X overlay; each side keeps its af fragments in registers ----
  bf16x8 af[8];
#pragma unroll 1
  for (int s = 0; s < 2; ++s) {
    {
      u16* X = LDS;
      const int wr = t & 7;
      const int h = ((wh << 3) + wr + off) & 63;
      const int wx = wwp * 2 + s;
      const int w0 = ((wx << 3) + off) & 63;  // 4-aligned -> no wrap inside run
      const int w1 = ((wx << 3) + off + 4) & 63;
      const int p0 = wr << 3;
#pragma unroll
      for (int it = 0; it < 4; ++it) {
        const int c = (t >> 3) + (it << 6);
        const float* src = x + ((size_t)(b * 256 + c) * 64 + h) * 64;
        float4 v0 = *(const float4*)(src + w0);
        float4 v1 = *(const float4*)(src + w1);
        X[(p0 + 0) * 264 + c] = f2bf(v0.x);
        X[(p0 + 1) * 264 + c] = f2bf(v0.y);
        X[(p0 + 2) * 264 + c] = f2bf(v0.z);
        X[(p0 + 3) * 264 + c] = f2bf(v0.w);
        X[(p0 + 4) * 264 + c] = f2bf(v1.x);
        X[(p0 + 5) * 264 + c] = f2bf(v1.y);
        X[(p0 + 6) * 264 + c] = f2bf(v1.z);
        X[(p0 + 7) * 264 + c] = f2bf(v1.w);
      }
    }
    __syncthreads();  // X(s) ready everywhere
    if (side == s) {
#pragma unroll
      for (int k = 0; k < 8; ++k)
        af[k] = *(const bf16x8*)&LDS[(wv * 16 + l15) * 264 + quad * 8 + k * 32];
    }
    asm volatile("s_waitcnt lgkmcnt(0)" ::: "memory");
    __syncthreads();  // af(s) in regs; X overlay free for next use
  }

  // prologue: stage unit 0 (h0 Q u0) -> BUF0
  stage1(wbf, LDS + BUF0, t);

  const int AT = ATT_BASE + side * ATT_STRIDE;
  const int QHs = AT, KHs = AT + KH_OFF, VTHs = AT + VTH_OFF;
  u16* Pw = LDS + AT + P_OFF + wv * 1152;  // per-wave P [16][72]

  f32x4 accP[16];  // proj acc: tile mt rows quad*4+r (c_out), col l15 (pos)
#pragma unroll
  for (int mt = 0; mt < 16; ++mt) accP[mt] = (f32x4){0.f, 0.f, 0.f, 0.f};

  const float scale = 0.17677669529663687f;  // 1/sqrt(32)
  bf16x8 bo;                                 // O fragment, live across u6->u7

  // 64 pipeline units (8 per head), ONE barrier each. Unit g:
  //   {vmcnt(0)+lgkmcnt(0); s_barrier; stage(g+1 -> other buf); compute(g)}
  // Both sides compute their own window's tile from the SAME staged weights.
#pragma unroll 1
  for (int h = 0; h < 8; ++h) {
    // ---- u0: Q u0 (BUF0) ----
    ENTRY();
    stage1(wbf + (size_t)(h * 2 + 1) * 4096, LDS + BUF1, t);  // Q u1
    QKV_TILE(BUF0, QHs, 0);
    // ---- u1: Q u1 (BUF1) ----
    ENTRY();
    stage1(wbf + (size_t)(16 + h * 2) * 4096, LDS + BUF0, t);  // K u0
    QKV_TILE(BUF1, QHs, 1);
    // ---- u2: K u0 (BUF0) ----
    ENTRY();
    stage1(wbf + (size_t)(17 + h * 2) * 4096, LDS + BUF1, t);  // K u1
    QKV_TILE(BUF0, KHs, 0);
    // ---- u3: K u1 (BUF1) ----
    ENTRY();
    stage1(wbf + (size_t)(32 + h * 2) * 4096, LDS + BUF0, t);  // V u0
    QKV_TILE(BUF1, KHs, 1);
    // ---- u4: V u0 (BUF0) ----
    ENTRY();
    stage1(wbf + (size_t)(33 + h * 2) * 4096, LDS + BUF1, t);  // V u1
    V_TILE(BUF0, 0);
    // ---- u5: V u1 (BUF1) ----
    ENTRY();
    stage1(wbf + 196608 + (size_t)h * 8192, LDS + BUF0, t);    // pj0
    V_TILE(BUF1, 1);
    // ---- u6: attention (own side's Q/K/V) + proj mt 0..7 (BUF0) ----
    ENTRY();
    stage1(wbf + 196608 + (size_t)h * 8192 + 4096, LDS + BUF1, t);  // pj1
    {
      bf16x8 aq = *(const bf16x8*)&LDS[QHs + (wv * 16 + l15) * 40 + quad * 8];
      f32x4 sc[4];
#pragma unroll
      for (int nt = 0; nt < 4; ++nt) {
        bf16x8 bk = *(const bf16x8*)&LDS[KHs + (nt * 16 + l15) * 40 + quad * 8];
        f32x4 z = {0.f, 0.f, 0.f, 0.f};
        sc[nt] = __builtin_amdgcn_mfma_f32_16x16x32_bf16(aq, bk, z, 0, 0, 0);
      }
#pragma unroll
      for (int r = 0; r < 4; ++r) {
        float mx = -1e30f;
#pragma unroll
        for (int nt = 0; nt < 4; ++nt) mx = fmaxf(mx, sc[nt][r]);
        mx = fmaxf(mx, __shfl_xor(mx, 1));
        mx = fmaxf(mx, __shfl_xor(mx, 2));
        mx = fmaxf(mx, __shfl_xor(mx, 4));
        mx = fmaxf(mx, __shfl_xor(mx, 8));  // row spans the 16-lane group
        float p[4], sum = 0.f;
#pragma unroll
        for (int nt = 0; nt < 4; ++nt) {
          p[nt] = __expf((sc[nt][r] - mx) * scale);
          sum += p[nt];
        }
        sum += __shfl_xor(sum, 1);
        sum += __shfl_xor(sum, 2);
        sum += __shfl_xor(sum, 4);
        sum += __shfl_xor(sum, 8);
        const float is = 1.f / sum;
#pragma unroll
        for (int nt = 0; nt < 4; ++nt)
          Pw[(quad * 4 + r) * 72 + nt * 16 + l15] = f2bf(p[nt] * is);
      }
      // PV (P write->read same wave: DS ops are in-order per wave)
      f32x4 oa[2];
      oa[0] = (f32x4){0.f, 0.f, 0.f, 0.f};
      oa[1] = (f32x4){0.f, 0.f, 0.f, 0.f};
#pragma unroll
      for (int kk = 0; kk < 2; ++kk) {
        bf16x8 ap = *(const bf16x8*)&Pw[l15 * 72 + kk * 32 + quad * 8];
#pragma unroll
        for (int n2 = 0; n2 < 2; ++n2) {
          bf16x8 bv =
              *(const bf16x8*)&LDS[VTHs + (n2 * 16 + l15) * 72 + kk * 32 + quad * 8];
          oa[n2] = __builtin_amdgcn_mfma_f32_16x16x32_bf16(ap, bv, oa[n2], 0, 0, 0);
        }
      }
      // O overwrites own Q rows (wave-private)
#pragma unroll
      for (int n2 = 0; n2 < 2; ++n2)
#pragma unroll
        for (int r = 0; r < 4; ++r)
          LDS[QHs + (pos0 + r) * 40 + n2 * 16 + l15] = f2bf(oa[n2][r]);
      // proj accumulate, first half: A = Wproj tiles 0..7 (BUF0), B = O rows
      bo = *(const bf16x8*)&LDS[QHs + (wv * 16 + l15) * 40 + quad * 8];
#pragma unroll
      for (int mt = 0; mt < 8; ++mt) {
        bf16x8 aw = *(const bf16x8*)&LDS[BUF0 + mt * 512 + lane * 8];
        accP[mt] = __builtin_amdgcn_mfma_f32_16x16x32_bf16(aw, bo, accP[mt], 0, 0, 0);
      }
    }
    // ---- u7: proj 8..15 (BUF1) ----
    ENTRY();
    if (h < 7)
      stage1(wbf + (size_t)((h + 1) * 2) * 4096, LDS + BUF0, t);  // next Q u0
#pragma unroll
    for (int mt = 0; mt < 8; ++mt) {
      bf16x8 aw = *(const bf16x8*)&LDS[BUF1 + mt * 512 + lane * 8];
      accP[8 + mt] =
          __builtin_amdgcn_mfma_f32_16x16x32_bf16(aw, bo, accP[8 + mt], 0, 0, 0);
    }
  }

  // ---- epilogue: C[c_out][pos] -> out[b][c][h][w] with roll(+4,+4) ----
  const int pos = wv * 16 + l15;
  const int hco = ((wh << 3) + (pos >> 3) + off) & 63;
  const int wco = ((ww << 3) + (pos & 7) + off) & 63;
#pragma unroll
  for (int mt = 0; mt < 16; ++mt)
#pragma unroll
    for (int r = 0; r < 4; ++r) {
      const int c = mt * 16 + quad * 4 + r;
      out[((size_t)(b * 256 + c) << 12) + (hco << 6) + wco] = accP[mt][r];
    }
}

extern "C" void kernel_launch(void* const* d_in, const int* in_sizes, int n_in,
                              void* d_out, int out_size, void* d_ws, size_t ws_size,
                              hipStream_t stream) {
  const float* x = (const float*)d_in[0];      // [16,256,64,64] f32
  const float* wqkv = (const float*)d_in[1];   // [768,256] f32
  const float* wproj = (const float*)d_in[2];  // [256,256] f32
  const int* shiftp = (const int*)d_in[3];     // scalar
  float* outp = (float*)d_out;                 // [16,256,64,64] f32
  u16* wbf = (u16*)d_ws;                       // 262144 u16 = 512 KB scratch
  hipLaunchKernelGGL(k_conv, dim3(128), dim3(256), 0, stream, wqkv, wproj, wbf);
  hipLaunchKernelGGL(k_fused, dim3(512), dim3(512), 0, stream, x, wbf, shiftp, outp);
}

// Round 5
// 221.555 us; speedup vs baseline: 1.0330x; 1.0330x over previous
//
#include <hip/hip_runtime.h>

typedef short bf16x8 __attribute__((ext_vector_type(8)));
typedef float f32x4 __attribute__((ext_vector_type(4)));
typedef unsigned short u16;
typedef unsigned int u32;

static __device__ __forceinline__ u16 f2bf(float f) {
  u32 u = __builtin_bit_cast(u32, f);
  u32 r = (u + 0x7FFFu + ((u >> 16) & 1u)) >> 16;  // RNE
  return (u16)r;
}

// ---- kernel 0: one-time f32 -> bf16 weight conversion + FRAGMENT SWIZZLE ----
// wqkv chunks (cid < 24576): tile = cid>>9 (tile = s*16+h*2+u), k = (cid>>6)&7,
//   lane = cid&63; 16B chunk = W[tile*16+(lane&15)][k*32+(lane>>4)*8 .. +8],
//   stored at wbf + cid*8 (linear).
// wproj (pid < 8192): mt = pid>>9, h = (pid>>6)&7, lane = pid&63 — stored
//   HEAD-MAJOR so each head's proj slice is contiguous (two 8 KB halves):
//   dst chunk = 24576 + h*1024 + mt*64 + lane.
__global__ __launch_bounds__(256) void k_conv(
    const float* __restrict__ wqkv, const float* __restrict__ wproj,
    u16* __restrict__ wbf) {
  const int cid = blockIdx.x * 256 + threadIdx.x;  // 128 blocks -> 32768 chunks
  const float* src;
  int dst;
  if (cid < 24576) {
    const int tile = cid >> 9, rem = cid & 511;
    const int k = rem >> 6, lane = rem & 63;
    src = wqkv + (size_t)(tile * 16 + (lane & 15)) * 256 + k * 32 + (lane >> 4) * 8;
    dst = cid;
  } else {
    const int pid = cid - 24576;
    const int mt = pid >> 9, rem = pid & 511;
    const int h = rem >> 6, lane = rem & 63;
    src = wproj + (size_t)(mt * 16 + (lane & 15)) * 256 + h * 32 + (lane >> 4) * 8;
    dst = 24576 + h * 1024 + mt * 64 + lane;
  }
  float4 f0 = *(const float4*)(src);
  float4 f1 = *(const float4*)(src + 4);
  ushort4 a, b;
  a.x = f2bf(f0.x); a.y = f2bf(f0.y); a.z = f2bf(f0.z); a.w = f2bf(f0.w);
  b.x = f2bf(f1.x); b.y = f2bf(f1.y); b.z = f2bf(f1.z); b.w = f2bf(f1.w);
  *(ushort4*)(wbf + (size_t)dst * 8) = a;
  *(ushort4*)(wbf + (size_t)dst * 8 + 4) = b;
}

// GEMM wave split: wave wv = wp*2 + wc; wp = pos half (32 rows), wc = c_out
// half. Each staged weight tile is read by 2 waves (not 4) and feeds 2
// independent MFMA chains (af0/af1) -> LDS-read volume halves, MFMA ILP 2x.
// Attention keeps the pos-split (wave owns rows wv*16..+15) -- verbatim math.
//
// LDS map (u16), ring of 4 stage buffers + attn region; X overlays the ring.
//   B0..B3 [0,16384)  8 KB stage buffers
//   QH 16384 (64x40) | KH 18944 (64x40) | VTH 21504 (32x72) | PH 23808
//   X overlay [0,16896) -- phase 1 only (dead before first DMA lands)
#define B0 0
#define B1 4096
#define B2 8192
#define B3 12288
#define QH 16384
#define KH 18944
#define VTH 21504
#define PH 23808
#define LDS_TOT 28416

#define MEMF() asm volatile("" ::: "memory")
#define BAR()                        \
  do {                               \
    MEMF();                          \
    __builtin_amdgcn_s_barrier();    \
    MEMF();                          \
  } while (0)
// Unit entry: drain own DMA + LDS ops, then barrier. After this the unit's
// staged pair is visible to all waves, and the buffers the upcoming stage
// overwrites have been fully read by everyone.
#define ENTRY()                                                      \
  do {                                                               \
    asm volatile("s_waitcnt vmcnt(0) lgkmcnt(0)" ::: "memory");      \
    __builtin_amdgcn_s_barrier();                                    \
    MEMF();                                                          \
  } while (0)
#define WLG0() asm volatile("s_waitcnt lgkmcnt(0)" ::: "memory")

#define GL2LDS(gp, lp)                                   \
  __builtin_amdgcn_global_load_lds(                      \
      (__attribute__((address_space(1))) void*)(gp),     \
      (__attribute__((address_space(3))) void*)(lp), 16, 0, 0)

// stage one 4096-u16 (8 KB) unit: 2 x global_load_lds dwordx4 per thread.
static __device__ __forceinline__ void stage_half(const u16* g, u16* l, int t) {
#pragma unroll
  for (int j = 0; j < 2; ++j) {
    const int off = (j * 256 + t) * 8;
    GL2LDS(g + off, l + off);
  }
}

// one 16-c_out tile x 32 own pos rows (2 subtiles, independent MFMA chains)
#define GEMM_TILE(BUFB, DSTB, U)                                              \
  do {                                                                        \
    const u16* wb_ = LDS + (BUFB) + lane * 8;                                 \
    f32x4 a0 = {0.f, 0.f, 0.f, 0.f}, a1 = {0.f, 0.f, 0.f, 0.f};               \
    _Pragma("unroll") for (int k = 0; k < 8; ++k) {                           \
      const bf16x8 bf_ = *(const bf16x8*)(wb_ + k * 512);                     \
      a0 = __builtin_amdgcn_mfma_f32_16x16x32_bf16(af0[k], bf_, a0, 0, 0, 0); \
      a1 = __builtin_amdgcn_mfma_f32_16x16x32_bf16(af1[k], bf_, a1, 0, 0, 0); \
    }                                                                         \
    _Pragma("unroll") for (int r = 0; r < 4; ++r) {                           \
      LDS[(DSTB) + (wp * 32 + quad * 4 + r) * 40 + (U) * 16 + l15] =          \
          f2bf(a0[r]);                                                        \
      LDS[(DSTB) + (wp * 32 + 16 + quad * 4 + r) * 40 + (U) * 16 + l15] =     \
          f2bf(a1[r]);                                                        \
    }                                                                         \
  } while (0)

// V tile -> VTH transposed [hd][pos], 32 own pos rows
#define VGEMM_TILE(BUFB, U)                                                   \
  do {                                                                        \
    const u16* wb_ = LDS + (BUFB) + lane * 8;                                 \
    f32x4 a0 = {0.f, 0.f, 0.f, 0.f}, a1 = {0.f, 0.f, 0.f, 0.f};               \
    _Pragma("unroll") for (int k = 0; k < 8; ++k) {                           \
      const bf16x8 bf_ = *(const bf16x8*)(wb_ + k * 512);                     \
      a0 = __builtin_amdgcn_mfma_f32_16x16x32_bf16(af0[k], bf_, a0, 0, 0, 0); \
      a1 = __builtin_amdgcn_mfma_f32_16x16x32_bf16(af1[k], bf_, a1, 0, 0, 0); \
    }                                                                         \
    ushort4 pk0, pk1;                                                         \
    pk0.x = f2bf(a0[0]); pk0.y = f2bf(a0[1]);                                 \
    pk0.z = f2bf(a0[2]); pk0.w = f2bf(a0[3]);                                 \
    pk1.x = f2bf(a1[0]); pk1.y = f2bf(a1[1]);                                 \
    pk1.z = f2bf(a1[2]); pk1.w = f2bf(a1[3]);                                 \
    *(ushort4*)&LDS[VTH + ((U) * 16 + l15) * 72 + wp * 32 + quad * 4] = pk0;  \
    *(ushort4*)&LDS[VTH + ((U) * 16 + l15) * 72 + wp * 32 + 16 + quad * 4] =  \
        pk1;                                                                  \
  } while (0)

__global__ __launch_bounds__(256, 2) void k_fused(
    const float* __restrict__ x, const u16* __restrict__ wbf,
    const int* __restrict__ shiftp, float* __restrict__ out) {
  __shared__ u16 LDS[LDS_TOT];
  // XCD-locality swizzle: the 8 windows sharing x/out cache lines (same b,wh)
  // get block IDs congruent mod 128 -> same XCD under round-robin dispatch.
  const int blk = blockIdx.x;
  const int win = ((blk & 127) << 3) | (blk >> 7);  // b*64 + wh*8 + ww
  const int b = win >> 6, wh = (win >> 3) & 7, ww = win & 7;
  const int off = (shiftp[0] != 0) ? 4 : 0;
  const int t = threadIdx.x;

  // stagger co-resident blocks to decorrelate phases
  {
    const int slot = (blk >> 8) & 3;
    if (slot == 1) __builtin_amdgcn_s_sleep(16);
    else if (slot == 2) __builtin_amdgcn_s_sleep(32);
    else if (slot == 3) __builtin_amdgcn_s_sleep(48);
  }

  // ---- phase 1: stage rolled X into LDS [pos][c] (f32 -> bf16) ----
  {
    u16* X = LDS;
    const int wr = t & 7;
    const int h = ((wh << 3) + wr + off) & 63;
    const int w0 = ((ww << 3) + off) & 63;  // 4-aligned -> no wrap inside run
    const int w1 = ((ww << 3) + off + 4) & 63;
    const int p0 = wr << 3;
#pragma unroll
    for (int it = 0; it < 8; ++it) {
      const int c = (t >> 3) + (it << 5);
      const float* src = x + ((size_t)(b * 256 + c) * 64 + h) * 64;
      float4 v0 = *(const float4*)(src + w0);
      float4 v1 = *(const float4*)(src + w1);
      X[(p0 + 0) * 264 + c] = f2bf(v0.x);
      X[(p0 + 1) * 264 + c] = f2bf(v0.y);
      X[(p0 + 2) * 264 + c] = f2bf(v0.z);
      X[(p0 + 3) * 264 + c] = f2bf(v0.w);
      X[(p0 + 4) * 264 + c] = f2bf(v1.x);
      X[(p0 + 5) * 264 + c] = f2bf(v1.y);
      X[(p0 + 6) * 264 + c] = f2bf(v1.z);
      X[(p0 + 7) * 264 + c] = f2bf(v1.w);
    }
  }
  __syncthreads();  // X ready (drains x loads -> vmcnt 0)

  const int lane = t & 63, wv = t >> 6;
  const int l15 = lane & 15, quad = lane >> 4;
  const int wp = wv >> 1, wc = wv & 1;     // GEMM split: pos half x c_out half
  const int apos0 = wv * 16 + quad * 4;    // attn row base (pos-split)

  // af for own 32 pos rows: two 16-row subtiles
  bf16x8 af0[8], af1[8];
#pragma unroll
  for (int k = 0; k < 8; ++k) {
    af0[k] = *(const bf16x8*)&LDS[(wp * 32 + l15) * 264 + quad * 8 + k * 32];
    af1[k] =
        *(const bf16x8*)&LDS[(wp * 32 + 16 + l15) * 264 + quad * 8 + k * 32];
  }
  WLG0();
  BAR();  // X fully read everywhere; ring + attn regions may now be written

  // prologue: stage pair for unit j0 of h0: {Q0 -> B0, K1 -> B1}
  stage_half(wbf, LDS + B0, t);
  stage_half(wbf + (size_t)17 * 4096, LDS + B1, t);

  f32x4 accP[8][2];  // proj acc: [local mt][pos subtile]; c = wc*128 + mt*16..
#pragma unroll
  for (int mt = 0; mt < 8; ++mt) {
    accP[mt][0] = (f32x4){0.f, 0.f, 0.f, 0.f};
    accP[mt][1] = (f32x4){0.f, 0.f, 0.f, 0.f};
  }

  const float scale = 0.17677669529663687f;  // 1/sqrt(32)
  u16* Pw = LDS + PH + wv * 1152;            // per-wave P [16][72]

  // 4 units per head, one barrier each (+1 mid-attn barrier for O):
  //   j0: wc0 Q0(B0)      | wc1 K1(B1)   ; stage {Q1->B2, V0->B3}
  //   j1: wc0 Q1(B2)      | wc1 V0(B3)   ; stage {K0->B0, V1->B1}
  //   j2: wc0 K0(B0)      | wc1 V1(B1)   ; stage {pj0->B2, pj1->B3}
  //   j3: attn + proj (wc0: pj0=B2, wc1: pj1=B3); stage {Q0',K1'} [h<7]
#pragma unroll 1
  for (int h = 0; h < 8; ++h) {
    // ---- j0 ----
    ENTRY();
    stage_half(wbf + (size_t)(h * 2 + 1) * 4096, LDS + B2, t);   // Q1
    stage_half(wbf + (size_t)(32 + h * 2) * 4096, LDS + B3, t);  // V0
    if (wc == 0) GEMM_TILE(B0, QH, 0);
    else GEMM_TILE(B1, KH, 1);
    // ---- j1 ----
    ENTRY();
    stage_half(wbf + (size_t)(16 + h * 2) * 4096, LDS + B0, t);  // K0
    stage_half(wbf + (size_t)(33 + h * 2) * 4096, LDS + B1, t);  // V1
    if (wc == 0) GEMM_TILE(B2, QH, 1);
    else VGEMM_TILE(B3, 0);
    // ---- j2 ----
    ENTRY();
    stage_half(wbf + 196608 + (size_t)h * 8192, LDS + B2, t);        // pj0
    stage_half(wbf + 196608 + (size_t)h * 8192 + 4096, LDS + B3, t); // pj1
    if (wc == 0) GEMM_TILE(B0, KH, 0);
    else VGEMM_TILE(B1, 1);
    // ---- j3: attention + proj ----
    ENTRY();
    if (h < 7) {
      stage_half(wbf + (size_t)((h + 1) * 2) * 4096, LDS + B0, t);   // Q0'
      stage_half(wbf + (size_t)(17 + (h + 1) * 2) * 4096, LDS + B1, t);  // K1'
    }
    {
      bf16x8 aq = *(const bf16x8*)&LDS[QH + (wv * 16 + l15) * 40 + quad * 8];
      f32x4 sc[4];
#pragma unroll
      for (int nt = 0; nt < 4; ++nt) {
        bf16x8 bk = *(const bf16x8*)&LDS[KH + (nt * 16 + l15) * 40 + quad * 8];
        f32x4 z = {0.f, 0.f, 0.f, 0.f};
        sc[nt] = __builtin_amdgcn_mfma_f32_16x16x32_bf16(aq, bk, z, 0, 0, 0);
      }
#pragma unroll
      for (int r = 0; r < 4; ++r) {
        float mx = -1e30f;
#pragma unroll
        for (int nt = 0; nt < 4; ++nt) mx = fmaxf(mx, sc[nt][r]);
        mx = fmaxf(mx, __shfl_xor(mx, 1));
        mx = fmaxf(mx, __shfl_xor(mx, 2));
        mx = fmaxf(mx, __shfl_xor(mx, 4));
        mx = fmaxf(mx, __shfl_xor(mx, 8));  // row spans the 16-lane group
        float p[4], sum = 0.f;
#pragma unroll
        for (int nt = 0; nt < 4; ++nt) {
          p[nt] = __expf((sc[nt][r] - mx) * scale);
          sum += p[nt];
        }
        sum += __shfl_xor(sum, 1);
        sum += __shfl_xor(sum, 2);
        sum += __shfl_xor(sum, 4);
        sum += __shfl_xor(sum, 8);
        const float is = 1.f / sum;
#pragma unroll
        for (int nt = 0; nt < 4; ++nt)
          Pw[(quad * 4 + r) * 72 + nt * 16 + l15] = f2bf(p[nt] * is);
      }
      // PV (P write->read same wave: DS ops are in-order per wave)
      f32x4 oa[2];
      oa[0] = (f32x4){0.f, 0.f, 0.f, 0.f};
      oa[1] = (f32x4){0.f, 0.f, 0.f, 0.f};
#pragma unroll
      for (int kk = 0; kk < 2; ++kk) {
        bf16x8 ap = *(const bf16x8*)&Pw[l15 * 72 + kk * 32 + quad * 8];
#pragma unroll
        for (int n2 = 0; n2 < 2; ++n2) {
          bf16x8 bv = *(const bf16x8*)&LDS[VTH + (n2 * 16 + l15) * 72 +
                                           kk * 32 + quad * 8];
          oa[n2] = __builtin_amdgcn_mfma_f32_16x16x32_bf16(ap, bv, oa[n2], 0, 0, 0);
        }
      }
      // O overwrites own Q rows
#pragma unroll
      for (int n2 = 0; n2 < 2; ++n2)
#pragma unroll
        for (int r = 0; r < 4; ++r)
          LDS[QH + (apos0 + r) * 40 + n2 * 16 + l15] = f2bf(oa[n2][r]);
    }
    WLG0();
    BAR();  // O visible across the wp-pair (proj reads both waves' O rows)
    {
      const int pjb = (wc == 0) ? B2 : B3;
      bf16x8 bo0 =
          *(const bf16x8*)&LDS[QH + (wp * 32 + l15) * 40 + quad * 8];
      bf16x8 bo1 =
          *(const bf16x8*)&LDS[QH + (wp * 32 + 16 + l15) * 40 + quad * 8];
#pragma unroll
      for (int mt = 0; mt < 8; ++mt) {
        bf16x8 aw = *(const bf16x8*)&LDS[pjb + mt * 512 + lane * 8];
        accP[mt][0] =
            __builtin_amdgcn_mfma_f32_16x16x32_bf16(aw, bo0, accP[mt][0], 0, 0, 0);
        accP[mt][1] =
            __builtin_amdgcn_mfma_f32_16x16x32_bf16(aw, bo1, accP[mt][1], 0, 0, 0);
      }
    }
  }

  // ---- epilogue: C[c_out][pos] -> out[b][c][h][w] with roll(+4,+4) ----
#pragma unroll
  for (int i = 0; i < 2; ++i) {
    const int pos = wp * 32 + i * 16 + l15;
    const int hco = ((wh << 3) + (pos >> 3) + off) & 63;
    const int wco = ((ww << 3) + (pos & 7) + off) & 63;
#pragma unroll
    for (int mt = 0; mt < 8; ++mt)
#pragma unroll
      for (int r = 0; r < 4; ++r) {
        const int c = wc * 128 + mt * 16 + quad * 4 + r;
        out[((size_t)(b * 256 + c) << 12) + (hco << 6) + wco] = accP[mt][i][r];
      }
  }
}

extern "C" void kernel_launch(void* const* d_in, const int* in_sizes, int n_in,
                              void* d_out, int out_size, void* d_ws, size_t ws_size,
                              hipStream_t stream) {
  const float* x = (const float*)d_in[0];      // [16,256,64,64] f32
  const float* wqkv = (const float*)d_in[1];   // [768,256] f32
  const float* wproj = (const float*)d_in[2];  // [256,256] f32
  const int* shiftp = (const int*)d_in[3];     // scalar
  float* outp = (float*)d_out;                 // [16,256,64,64] f32
  u16* wbf = (u16*)d_ws;                       // 262144 u16 = 512 KB scratch
  hipLaunchKernelGGL(k_conv, dim3(128), dim3(256), 0, stream, wqkv, wproj, wbf);
  hipLaunchKernelGGL(k_fused, dim3(1024), dim3(256), 0, stream, x, wbf, shiftp, outp);
}

// Round 6
// 211.728 us; speedup vs baseline: 1.0810x; 1.0464x over previous
//
#include <hip/hip_runtime.h>

typedef short bf16x8 __attribute__((ext_vector_type(8)));
typedef float f32x4 __attribute__((ext_vector_type(4)));
typedef unsigned short u16;
typedef unsigned int u32;

static __device__ __forceinline__ u16 f2bf(float f) {
  u32 u = __builtin_bit_cast(u32, f);
  u32 r = (u + 0x7FFFu + ((u >> 16) & 1u)) >> 16;  // RNE
  return (u16)r;
}

// ---- kernel 0: one-time f32 -> bf16 weight conversion + FRAGMENT SWIZZLE ----
// wqkv chunks (cid < 24576): tile = cid>>9 (tile = s*16+h*2+u), k = (cid>>6)&7,
//   lane = cid&63; 16B chunk = W[tile*16+(lane&15)][k*32+(lane>>4)*8 .. +8],
//   stored at wbf + cid*8 (linear).
// wproj (pid < 8192): mt = pid>>9, h = (pid>>6)&7, lane = pid&63 — stored
//   HEAD-MAJOR: dst chunk = 24576 + h*1024 + mt*64 + lane.
__global__ __launch_bounds__(256) void k_conv(
    const float* __restrict__ wqkv, const float* __restrict__ wproj,
    u16* __restrict__ wbf) {
  const int cid = blockIdx.x * 256 + threadIdx.x;  // 128 blocks -> 32768 chunks
  const float* src;
  int dst;
  if (cid < 24576) {
    const int tile = cid >> 9, rem = cid & 511;
    const int k = rem >> 6, lane = rem & 63;
    src = wqkv + (size_t)(tile * 16 + (lane & 15)) * 256 + k * 32 + (lane >> 4) * 8;
    dst = cid;
  } else {
    const int pid = cid - 24576;
    const int mt = pid >> 9, rem = pid & 511;
    const int h = rem >> 6, lane = rem & 63;
    src = wproj + (size_t)(mt * 16 + (lane & 15)) * 256 + h * 32 + (lane >> 4) * 8;
    dst = 24576 + h * 1024 + mt * 64 + lane;
  }
  float4 f0 = *(const float4*)(src);
  float4 f1 = *(const float4*)(src + 4);
  ushort4 a, b;
  a.x = f2bf(f0.x); a.y = f2bf(f0.y); a.z = f2bf(f0.z); a.w = f2bf(f0.w);
  b.x = f2bf(f1.x); b.y = f2bf(f1.y); b.z = f2bf(f1.z); b.w = f2bf(f1.w);
  *(ushort4*)(wbf + (size_t)dst * 8) = a;
  *(ushort4*)(wbf + (size_t)dst * 8 + 4) = b;
}

// v6: weights come DIRECTLY from L2 via per-wave global b128 register loads
// (R0's verified address math) with a 2-tile register lookahead. No
// global_load_lds, no staging ring, no vmcnt in the loop: weight loads are
// wave-private and stay in flight ACROSS barriers. Barriers only at intrinsic
// cross-wave exchanges: QKV publish, O publish, region reuse (3 per head).
//
// GEMM wave split (R5): wave wv = wp*2 + wc; wp = pos half (32 rows), wc =
// tile half. Attention keeps the pos-split (wave owns rows wv*16..+15).
//
// LDS (u16): attn region only; X [64][264] overlays it during phase 1.
//   QH 0 (64x40) | KH 2560 (64x40) | VTH 5120 (32x72) | PH 7424 (4x[16][72])
#define QH 0
#define KH 2560
#define VTH 5120
#define PH 7424
#define LDS_TOT 16896

#define MEMF() asm volatile("" ::: "memory")
#define BAR()                        \
  do {                               \
    MEMF();                          \
    __builtin_amdgcn_s_barrier();    \
    MEMF();                          \
  } while (0)
#define WLG0() asm volatile("s_waitcnt lgkmcnt(0)" ::: "memory")

// load one tile's 8 B-fragments into a register array (b128 from L2)
#define LOADF(FR, TI)                                              \
  do {                                                             \
    const u16* fp_ = wbf + (size_t)(TI) * 4096 + lane * 8;         \
    _Pragma("unroll") for (int k = 0; k < 8; ++k)                  \
        FR[k] = *(const bf16x8*)(fp_ + k * 512);                   \
  } while (0)

// one 16-c_out tile x 32 own pos rows from register frags (2 indep chains)
#define GEMM_TILE_F(FR, DSTB, U)                                              \
  do {                                                                        \
    f32x4 a0 = {0.f, 0.f, 0.f, 0.f}, a1 = {0.f, 0.f, 0.f, 0.f};               \
    _Pragma("unroll") for (int k = 0; k < 8; ++k) {                           \
      a0 = __builtin_amdgcn_mfma_f32_16x16x32_bf16(af0[k], FR[k], a0, 0, 0, 0);\
      a1 = __builtin_amdgcn_mfma_f32_16x16x32_bf16(af1[k], FR[k], a1, 0, 0, 0);\
    }                                                                         \
    _Pragma("unroll") for (int r = 0; r < 4; ++r) {                           \
      LDS[(DSTB) + (wp * 32 + quad * 4 + r) * 40 + (U) * 16 + l15] =          \
          f2bf(a0[r]);                                                        \
      LDS[(DSTB) + (wp * 32 + 16 + quad * 4 + r) * 40 + (U) * 16 + l15] =     \
          f2bf(a1[r]);                                                        \
    }                                                                         \
  } while (0)

// V tile -> VTH transposed [hd][pos], from register frags
#define V_TILE_F(FR, U)                                                       \
  do {                                                                        \
    f32x4 a0 = {0.f, 0.f, 0.f, 0.f}, a1 = {0.f, 0.f, 0.f, 0.f};               \
    _Pragma("unroll") for (int k = 0; k < 8; ++k) {                           \
      a0 = __builtin_amdgcn_mfma_f32_16x16x32_bf16(af0[k], FR[k], a0, 0, 0, 0);\
      a1 = __builtin_amdgcn_mfma_f32_16x16x32_bf16(af1[k], FR[k], a1, 0, 0, 0);\
    }                                                                         \
    ushort4 pk0, pk1;                                                         \
    pk0.x = f2bf(a0[0]); pk0.y = f2bf(a0[1]);                                 \
    pk0.z = f2bf(a0[2]); pk0.w = f2bf(a0[3]);                                 \
    pk1.x = f2bf(a1[0]); pk1.y = f2bf(a1[1]);                                 \
    pk1.z = f2bf(a1[2]); pk1.w = f2bf(a1[3]);                                 \
    *(ushort4*)&LDS[VTH + ((U) * 16 + l15) * 72 + wp * 32 + quad * 4] = pk0;  \
    *(ushort4*)&LDS[VTH + ((U) * 16 + l15) * 72 + wp * 32 + 16 + quad * 4] =  \
        pk1;                                                                  \
  } while (0)

__global__ __launch_bounds__(256, 2) void k_fused(
    const float* __restrict__ x, const u16* __restrict__ wbf,
    const int* __restrict__ shiftp, float* __restrict__ out) {
  __shared__ u16 LDS[LDS_TOT];
  // XCD-locality swizzle: the 8 windows sharing x/out cache lines (same b,wh)
  // get block IDs congruent mod 128 -> same XCD under round-robin dispatch.
  const int blk = blockIdx.x;
  const int win = ((blk & 127) << 3) | (blk >> 7);  // b*64 + wh*8 + ww
  const int b = win >> 6, wh = (win >> 3) & 7, ww = win & 7;
  const int off = (shiftp[0] != 0) ? 4 : 0;
  const int t = threadIdx.x;

  // stagger co-resident blocks to decorrelate phases
  {
    const int slot = (blk >> 8) & 3;
    if (slot == 1) __builtin_amdgcn_s_sleep(16);
    else if (slot == 2) __builtin_amdgcn_s_sleep(32);
    else if (slot == 3) __builtin_amdgcn_s_sleep(48);
  }

  // ---- phase 1: stage rolled X into LDS [pos][c] (f32 -> bf16) ----
  {
    u16* X = LDS;
    const int wr = t & 7;
    const int h = ((wh << 3) + wr + off) & 63;
    const int w0 = ((ww << 3) + off) & 63;  // 4-aligned -> no wrap inside run
    const int w1 = ((ww << 3) + off + 4) & 63;
    const int p0 = wr << 3;
#pragma unroll
    for (int it = 0; it < 8; ++it) {
      const int c = (t >> 3) + (it << 5);
      const float* src = x + ((size_t)(b * 256 + c) * 64 + h) * 64;
      float4 v0 = *(const float4*)(src + w0);
      float4 v1 = *(const float4*)(src + w1);
      X[(p0 + 0) * 264 + c] = f2bf(v0.x);
      X[(p0 + 1) * 264 + c] = f2bf(v0.y);
      X[(p0 + 2) * 264 + c] = f2bf(v0.z);
      X[(p0 + 3) * 264 + c] = f2bf(v0.w);
      X[(p0 + 4) * 264 + c] = f2bf(v1.x);
      X[(p0 + 5) * 264 + c] = f2bf(v1.y);
      X[(p0 + 6) * 264 + c] = f2bf(v1.z);
      X[(p0 + 7) * 264 + c] = f2bf(v1.w);
    }
  }
  __syncthreads();  // X ready (drains x loads)

  const int lane = t & 63, wv = t >> 6;
  const int l15 = lane & 15, quad = lane >> 4;
  const int wp = wv >> 1, wc = wv & 1;   // GEMM split: pos half x tile half
  const int apos0 = wv * 16 + quad * 4;  // attn row base (pos-split)

  // af for own 32 pos rows: two 16-row subtiles
  bf16x8 af0[8], af1[8];
#pragma unroll
  for (int k = 0; k < 8; ++k) {
    af0[k] = *(const bf16x8*)&LDS[(wp * 32 + l15) * 264 + quad * 8 + k * 32];
    af1[k] =
        *(const bf16x8*)&LDS[(wp * 32 + 16 + l15) * 264 + quad * 8 + k * 32];
  }
  WLG0();
  BAR();  // X fully read everywhere; attn region may now be written

  f32x4 accP[8][2];  // proj acc: [local mt][pos subtile]; c = wc*128 + mt*16..
#pragma unroll
  for (int mt = 0; mt < 8; ++mt) {
    accP[mt][0] = (f32x4){0.f, 0.f, 0.f, 0.f};
    accP[mt][1] = (f32x4){0.f, 0.f, 0.f, 0.f};
  }

  const float scale = 0.17677669529663687f;  // 1/sqrt(32)
  u16* Pw = LDS + PH + wv * 1152;            // per-wave P [16][72]

  // Per head: wc0 computes {Q0,Q1,K0}, wc1 computes {K1,V0,V1}; weight frags
  // register-pipelined 2 tiles ahead. 3 barriers/head, none draining vmcnt.
#pragma unroll 1
  for (int h = 0; h < 8; ++h) {
    {
      bf16x8 fA[8], fB[8];
      const int t0 = wc ? (17 + h * 2) : (h * 2);       // K1 | Q0
      const int t1 = wc ? (32 + h * 2) : (h * 2 + 1);   // V0 | Q1
      const int t2 = wc ? (33 + h * 2) : (16 + h * 2);  // V1 | K0
      LOADF(fA, t0);
      LOADF(fB, t1);
      if (wc == 0) GEMM_TILE_F(fA, QH, 0); else GEMM_TILE_F(fA, KH, 1);
      LOADF(fA, t2);
      if (wc == 0) GEMM_TILE_F(fB, QH, 1); else V_TILE_F(fB, 0);
      if (wc == 0) GEMM_TILE_F(fA, KH, 0); else V_TILE_F(fA, 1);
    }
    WLG0();
    BAR();  // QKV published
    {
      bf16x8 aq = *(const bf16x8*)&LDS[QH + (wv * 16 + l15) * 40 + quad * 8];
      f32x4 sc[4];
#pragma unroll
      for (int nt = 0; nt < 4; ++nt) {
        bf16x8 bk = *(const bf16x8*)&LDS[KH + (nt * 16 + l15) * 40 + quad * 8];
        f32x4 z = {0.f, 0.f, 0.f, 0.f};
        sc[nt] = __builtin_amdgcn_mfma_f32_16x16x32_bf16(aq, bk, z, 0, 0, 0);
      }
#pragma unroll
      for (int r = 0; r < 4; ++r) {
        float mx = -1e30f;
#pragma unroll
        for (int nt = 0; nt < 4; ++nt) mx = fmaxf(mx, sc[nt][r]);
        mx = fmaxf(mx, __shfl_xor(mx, 1));
        mx = fmaxf(mx, __shfl_xor(mx, 2));
        mx = fmaxf(mx, __shfl_xor(mx, 4));
        mx = fmaxf(mx, __shfl_xor(mx, 8));  // row spans the 16-lane group
        float p[4], sum = 0.f;
#pragma unroll
        for (int nt = 0; nt < 4; ++nt) {
          p[nt] = __expf((sc[nt][r] - mx) * scale);
          sum += p[nt];
        }
        sum += __shfl_xor(sum, 1);
        sum += __shfl_xor(sum, 2);
        sum += __shfl_xor(sum, 4);
        sum += __shfl_xor(sum, 8);
        const float is = 1.f / sum;
#pragma unroll
        for (int nt = 0; nt < 4; ++nt)
          Pw[(quad * 4 + r) * 72 + nt * 16 + l15] = f2bf(p[nt] * is);
      }
      // PV (P write->read same wave: DS ops are in-order per wave)
      f32x4 oa[2];
      oa[0] = (f32x4){0.f, 0.f, 0.f, 0.f};
      oa[1] = (f32x4){0.f, 0.f, 0.f, 0.f};
#pragma unroll
      for (int kk = 0; kk < 2; ++kk) {
        bf16x8 ap = *(const bf16x8*)&Pw[l15 * 72 + kk * 32 + quad * 8];
#pragma unroll
        for (int n2 = 0; n2 < 2; ++n2) {
          bf16x8 bv = *(const bf16x8*)&LDS[VTH + (n2 * 16 + l15) * 72 +
                                           kk * 32 + quad * 8];
          oa[n2] = __builtin_amdgcn_mfma_f32_16x16x32_bf16(ap, bv, oa[n2], 0, 0, 0);
        }
      }
      // O overwrites own Q rows
#pragma unroll
      for (int n2 = 0; n2 < 2; ++n2)
#pragma unroll
        for (int r = 0; r < 4; ++r)
          LDS[QH + (apos0 + r) * 40 + n2 * 16 + l15] = f2bf(oa[n2][r]);
    }
    // proj weight frags for this head (stay in flight across the O barrier)
    bf16x8 pjf[8];
    {
      const u16* pp_ =
          wbf + 196608 + (size_t)h * 8192 + (size_t)wc * 4096 + lane * 8;
#pragma unroll
      for (int j = 0; j < 8; ++j) pjf[j] = *(const bf16x8*)(pp_ + j * 512);
    }
    WLG0();
    BAR();  // O visible across the wp-pair
    {
      bf16x8 bo0 = *(const bf16x8*)&LDS[QH + (wp * 32 + l15) * 40 + quad * 8];
      bf16x8 bo1 =
          *(const bf16x8*)&LDS[QH + (wp * 32 + 16 + l15) * 40 + quad * 8];
#pragma unroll
      for (int mt = 0; mt < 8; ++mt) {
        accP[mt][0] =
            __builtin_amdgcn_mfma_f32_16x16x32_bf16(pjf[mt], bo0, accP[mt][0], 0, 0, 0);
        accP[mt][1] =
            __builtin_amdgcn_mfma_f32_16x16x32_bf16(pjf[mt], bo1, accP[mt][1], 0, 0, 0);
      }
    }
    WLG0();
    BAR();  // all LDS reads done; next head may overwrite Q/K/VT
  }

  // ---- epilogue: C[c_out][pos] -> out[b][c][h][w] with roll(+4,+4) ----
#pragma unroll
  for (int i = 0; i < 2; ++i) {
    const int pos = wp * 32 + i * 16 + l15;
    const int hco = ((wh << 3) + (pos >> 3) + off) & 63;
    const int wco = ((ww << 3) + (pos & 7) + off) & 63;
#pragma unroll
    for (int mt = 0; mt < 8; ++mt)
#pragma unroll
      for (int r = 0; r < 4; ++r) {
        const int c = wc * 128 + mt * 16 + quad * 4 + r;
        out[((size_t)(b * 256 + c) << 12) + (hco << 6) + wco] = accP[mt][i][r];
      }
  }
}

extern "C" void kernel_launch(void* const* d_in, const int* in_sizes, int n_in,
                              void* d_out, int out_size, void* d_ws, size_t ws_size,
                              hipStream_t stream) {
  const float* x = (const float*)d_in[0];      // [16,256,64,64] f32
  const float* wqkv = (const float*)d_in[1];   // [768,256] f32
  const float* wproj = (const float*)d_in[2];  // [256,256] f32
  const int* shiftp = (const int*)d_in[3];     // scalar
  float* outp = (float*)d_out;                 // [16,256,64,64] f32
  u16* wbf = (u16*)d_ws;                       // 262144 u16 = 512 KB scratch
  hipLaunchKernelGGL(k_conv, dim3(128), dim3(256), 0, stream, wqkv, wproj, wbf);
  hipLaunchKernelGGL(k_fused, dim3(1024), dim3(256), 0, stream, x, wbf, shiftp, outp);
}